// Round 9
// baseline (265.188 us; speedup 1.0000x reference)
//
#include <hip/hip_runtime.h>
#include <stdint.h>
#include <math.h>

// ---------------- problem constants ----------------
namespace {
constexpr int Bn = 512, Dn = 128, Wn = 30, Kn = 5;
constexpr int HWn = 900;   // 30*30
constexpr int TQ  = 225;   // float4 pixel-quads per image

// workspace float offsets (~3.7 MB)
constexpr size_t OFF_A  = 0;                          // Kn*Dn = 640
constexpr size_t OFF_SA = OFF_A + (size_t)Kn * Dn;    // 5 (pad 8)
constexpr size_t OFF_C0 = OFF_SA + 8;                 // 5 (pad 8)
constexpr size_t OFF_R  = OFF_C0 + 8;                 // Bn*HWn
constexpr size_t OFF_MR = OFF_R + (size_t)Bn * HWn;   // Bn*HWn

// output float offsets (centroids, attention_maps, stop_logits concatenated)
// OUT_ATTN doubles as scratch: k_base writes base scores there, k_rest
// overwrites them in place with the attention maps.
constexpr size_t OUT_CENT = 0;
constexpr size_t OUT_ATTN = (size_t)Bn * Kn * 2;               // 5120
constexpr size_t OUT_STOP = OUT_ATTN + (size_t)Bn * Kn * HWn;  // 2309120
}  // namespace

struct FoldedKeys { uint32_t k1[5]; uint32_t k2[5]; };

// ---------------- threefry2x32 (JAX partitionable, 20 rounds) ----------------
__host__ __device__ static inline uint32_t rotl32(uint32_t x, int d) {
  return (x << d) | (x >> (32 - d));
}

__host__ __device__ static inline void threefry2x32(uint32_t k1, uint32_t k2,
                                                    uint32_t& x0, uint32_t& x1) {
  uint32_t k3 = k1 ^ k2 ^ 0x1BD11BDAu;
  x0 += k1; x1 += k2;
#define TF_R(rot) { x0 += x1; x1 = rotl32(x1, rot); x1 ^= x0; }
  TF_R(13) TF_R(15) TF_R(26) TF_R(6)   x0 += k2; x1 += k3 + 1u;
  TF_R(17) TF_R(29) TF_R(16) TF_R(24)  x0 += k3; x1 += k1 + 2u;
  TF_R(13) TF_R(15) TF_R(26) TF_R(6)   x0 += k1; x1 += k2 + 3u;
  TF_R(17) TF_R(29) TF_R(16) TF_R(24)  x0 += k2; x1 += k3 + 4u;
  TF_R(13) TF_R(15) TF_R(26) TF_R(6)   x0 += k3; x1 += k1 + 5u;
#undef TF_R
}

// ---------------- reduction helpers ----------------
__device__ static inline float wsum(float v) {
#pragma unroll
  for (int o = 32; o; o >>= 1) v += __shfl_xor(v, o, 64);
  return v;
}
__device__ static inline float wmaxr(float v) {
#pragma unroll
  for (int o = 32; o; o >>= 1) v = fmaxf(v, __shfl_xor(v, o, 64));
  return v;
}
__device__ static inline float bsum4(float v, float* scr) {  // 256-thread block
  v = wsum(v);
  if ((threadIdx.x & 63) == 0) scr[threadIdx.x >> 6] = v;
  __syncthreads();
  float r = scr[0] + scr[1] + scr[2] + scr[3];
  __syncthreads();
  return r;
}
__device__ static inline float bmax4(float v, float* scr) {
  v = wmaxr(v);
  if ((threadIdx.x & 63) == 0) scr[threadIdx.x >> 6] = v;
  __syncthreads();
  float r = fmaxf(fmaxf(scr[0], scr[1]), fmaxf(scr[2], scr[3]));
  __syncthreads();
  return r;
}
__device__ static inline float bsum2(float v, float* scr) {  // 128-thread block
  v = wsum(v);
  if ((threadIdx.x & 63) == 0) scr[threadIdx.x >> 6] = v;
  __syncthreads();
  float r = scr[0] + scr[1];
  __syncthreads();
  return r;
}

// ---------------- kernel 0: per-query constants ----------------
__global__ __launch_bounds__(128) void k_prep(
    const float* __restrict__ clue, const float* __restrict__ wq,
    const float* __restrict__ bq, const float* __restrict__ wk,
    const float* __restrict__ bk, const float* __restrict__ qn_g,
    const float* __restrict__ qn_b, const float* __restrict__ fn_g,
    const float* __restrict__ fn_b, float* __restrict__ ws) {
  __shared__ float scr[2];
  __shared__ float lnc[Dn], qrow[Dn], qkrow[Dn];
  const int k = blockIdx.x, t = threadIdx.x;
  float xv = clue[(size_t)k * Dn + t];
  float m = bsum2(xv, scr) * (1.0f / Dn);
  float dd = xv - m;
  float var = bsum2(dd * dd, scr) * (1.0f / Dn);
  float r = 1.0f / sqrtf(var + 1e-5f);
  lnc[t] = dd * r * qn_g[t] + qn_b[t];
  __syncthreads();
  {
    float acc = bq[t];
    const float* wr = wq + (size_t)t * Dn;
    for (int e = 0; e < Dn; ++e) acc += lnc[e] * wr[e];
    qrow[t] = acc;
  }
  __syncthreads();
  {
    float acc = 0.f;
    for (int d = 0; d < Dn; ++d) acc += qrow[d] * wk[(size_t)d * Dn + t];
    qkrow[t] = acc;
    ws[OFF_A + (size_t)k * Dn + t] = fn_g[t] * acc;
  }
  __syncthreads();
  float sa = bsum2(fn_g[t] * qkrow[t], scr);
  float c0 = bsum2(fn_b[t] * qkrow[t] + qrow[t] * bk[t], scr);
  if (t == 0) {
    ws[OFF_SA + k] = sa;
    ws[OFF_C0 + k] = c0;
  }
}

// ---------------- kernel 1: LN stats + base scores (HBM-heavy pass) ---------
// grid (2, B) x 256 thr; thread = pixel-pair; ~46 VGPR -> fits the 64-VGPR
// allocator target WITHOUT spilling -> 8 blocks/CU = 32 waves/CU.
__global__ __launch_bounds__(256) void k_base(const float* __restrict__ x,
                                              float* __restrict__ ws,
                                              float* __restrict__ out) {
  __shared__ float Al[Kn * Dn];
  const int b = blockIdx.y, half = blockIdx.x, t = threadIdx.x;
  for (int i = t; i < Kn * Dn; i += 256) Al[i] = ws[OFF_A + i];
  __syncthreads();
  const bool act = (t < TQ);
  const int P = half * TQ + (act ? t : 0);  // pair index 0..449
  const float2* xt = (const float2*)(x + (size_t)b * Dn * HWn) + P;

  float sm[2] = {0, 0}, sq[2] = {0, 0};
  float sd[5][2] = {};
  for (int e0 = 0; e0 < Dn; e0 += 8) {
    float2 vb[8];
#pragma unroll
    for (int j = 0; j < 8; ++j) vb[j] = xt[(size_t)(e0 + j) * (HWn / 2)];
#pragma unroll
    for (int j = 0; j < 8; ++j) {
      const int e = e0 + j;
      float a0 = Al[e], a1 = Al[Dn + e], a2 = Al[2 * Dn + e],
            a3 = Al[3 * Dn + e], a4 = Al[4 * Dn + e];
      float vv[2] = {vb[j].x, vb[j].y};
#pragma unroll
      for (int c = 0; c < 2; ++c) {
        sm[c] += vv[c];
        sq[c] += vv[c] * vv[c];
        sd[0][c] += vv[c] * a0; sd[1][c] += vv[c] * a1;
        sd[2][c] += vv[c] * a2; sd[3][c] += vv[c] * a3;
        sd[4][c] += vv[c] * a4;
      }
    }
  }
  if (!act) return;
  float SA[5], C0[5];
#pragma unroll
  for (int k = 0; k < 5; ++k) { SA[k] = ws[OFF_SA + k]; C0[k] = ws[OFF_C0 + k]; }
  float r[2], m[2];
#pragma unroll
  for (int c = 0; c < 2; ++c) {
    m[c] = sm[c] * (1.0f / Dn);
    float var = sq[c] * (1.0f / Dn) - m[c] * m[c];
    r[c] = 1.0f / sqrtf(var + 1e-5f);
  }
  const int n0 = 2 * P;
  *(float2*)&ws[OFF_R + (size_t)b * HWn + n0] = make_float2(r[0], r[1]);
  *(float2*)&ws[OFF_MR + (size_t)b * HWn + n0] =
      make_float2(m[0] * r[0], m[1] * r[1]);
#pragma unroll
  for (int k = 0; k < 5; ++k) {
    float b0 = (r[0] * (sd[k][0] - m[0] * SA[k]) + C0[k]) * 0.08838834764831844f;
    float b1 = (r[1] * (sd[k][1] - m[1] * SA[k]) + C0[k]) * 0.08838834764831844f;
    *(float2*)&out[OUT_ATTN + ((size_t)(b * Kn + k)) * HWn + n0] =
        make_float2(b0, b1);
  }
}

// ---------------- kernel 2: gumbel loop + dots + MLP (per image) ------------
// grid (B) x 256 thr; block handles image rb = Bn-1-bid (reverse order so the
// features it re-reads are the ones k_base streamed most recently -> L3-hot).
// Phase B: 5 gumbel-softmax steps; attn->out in place, w=attn*rstd->LDS.
// Phase C: attended dots from L3. Phase D: LN-combine + wv + GELU MLP + stop.
__global__ __launch_bounds__(256) void k_rest(
    const float* __restrict__ x, const float* __restrict__ ws,
    const float* __restrict__ wv, const float* __restrict__ bv,
    const float* __restrict__ sw1, const float* __restrict__ sb1,
    const float* __restrict__ sw2, const float* __restrict__ sb2,
    const float* __restrict__ fn_g, const float* __restrict__ fn_b,
    float* __restrict__ out, FoldedKeys keys) {
  __shared__ float wl[Kn * HWn];  // w = attn*rstd (18 KB)
  __shared__ float dots[Kn * Dn];
  __shared__ float af[Kn * Dn];
  __shared__ float att[Kn * Dn];
  __shared__ float hbuf[Kn * 64];
  __shared__ float scr4[4];
  __shared__ float scr16[16];
  __shared__ float caL[8], entL[8];
  const int b = Bn - 1 - blockIdx.x;  // reverse for L3 locality
  const int t = threadIdx.x;
  const bool act = (t < TQ);
  const int t4 = 4 * (act ? t : 0);

  // ---- phase B: 5 sequential gumbel-softmax steps ----
  float r[4], mr[4], cum[4], rw[4], cl[4];
  {
    float4 rv = make_float4(0, 0, 0, 0), mv = make_float4(0, 0, 0, 0);
    if (act) {
      rv = *(const float4*)&ws[OFF_R + (size_t)b * HWn + t4];
      mv = *(const float4*)&ws[OFF_MR + (size_t)b * HWn + t4];
    }
    r[0] = rv.x; r[1] = rv.y; r[2] = rv.z; r[3] = rv.w;
    mr[0] = mv.x; mr[1] = mv.y; mr[2] = mv.z; mr[3] = mv.w;
#pragma unroll
    for (int c = 0; c < 4; ++c) {
      cum[c] = 1.0f;
      int n = t4 + c;
      rw[c] = (float)(n / Wn);
      cl[c] = (float)(n % Wn);
    }
  }
  for (int k = 0; k < 5; ++k) {
    const uint32_t fk1 = keys.k1[k], fk2 = keys.k2[k];
    float base4[4] = {0, 0, 0, 0};
    if (act) {
      float4 bv4 = *(const float4*)&out[OUT_ATTN + ((size_t)(b * Kn + k)) * HWn + t4];
      base4[0] = bv4.x; base4[1] = bv4.y; base4[2] = bv4.z; base4[3] = bv4.w;
    }
    float noisy[4];
#pragma unroll
    for (int c = 0; c < 4; ++c) {
      if (act) {
        float s = base4[c] + logf(cum[c]);
        s = fminf(fmaxf(s, -50.f), 50.f);
        uint32_t j = (uint32_t)(b * HWn + t4 + c);
        uint32_t x0 = 0u, x1 = j;  // partitionable counter = (0, j)
        threefry2x32(fk1, fk2, x0, x1);
        uint32_t bits = x0 ^ x1;
        float u = __uint_as_float((bits >> 9) | 0x3f800000u) - 1.0f;
        u = fmaxf(u, 1e-10f);
        float g = -logf(-logf(u));
        noisy[c] = fminf(fmaxf(s + g, -50.f), 50.f);
      } else {
        noisy[c] = -1e30f;
      }
    }
    float lm = fmaxf(fmaxf(noisy[0], noisy[1]), fmaxf(noisy[2], noisy[3]));
    const float M = bmax4(lm, scr4);
    float p[4], ls = 0.f;
#pragma unroll
    for (int c = 0; c < 4; ++c) {
      p[c] = act ? expf(noisy[c] - M) : 0.f;
      ls += p[c];
    }
    const float Z = bsum4(ls, scr4);
    const float inv = 1.0f / Z;
    float red[4] = {0, 0, 0, 0};  // cr, cc, ea, ca
    float av[4];
#pragma unroll
    for (int c = 0; c < 4; ++c) {
      float a = p[c] * inv;
      av[c] = a;
      if (act) {
        red[0] += a * rw[c];
        red[1] += a * cl[c];
        float ac = fmaxf(a, 1e-10f);
        red[2] += ac * logf(ac);
        red[3] += a * mr[c];
        cum[c] = fmaxf(cum[c] * (1.0f - 0.9f * a), 1e-6f);
      }
    }
    if (act) {
      *(float4*)&out[OUT_ATTN + ((size_t)(b * Kn + k)) * HWn + t4] =
          make_float4(av[0], av[1], av[2], av[3]);
      *(float4*)&wl[(size_t)k * HWn + t4] =
          make_float4(av[0] * r[0], av[1] * r[1], av[2] * r[2], av[3] * r[3]);
    }
#pragma unroll
    for (int j2 = 0; j2 < 4; ++j2) red[j2] = wsum(red[j2]);
    if ((t & 63) == 0) {
      int w = t >> 6;
      scr16[w * 4 + 0] = red[0]; scr16[w * 4 + 1] = red[1];
      scr16[w * 4 + 2] = red[2]; scr16[w * 4 + 3] = red[3];
    }
    __syncthreads();
    if (t == 0) {
      float cr = scr16[0] + scr16[4] + scr16[8] + scr16[12];
      float cc = scr16[1] + scr16[5] + scr16[9] + scr16[13];
      float ea = scr16[2] + scr16[6] + scr16[10] + scr16[14];
      float ca = scr16[3] + scr16[7] + scr16[11] + scr16[15];
      out[OUT_CENT + ((size_t)(b * Kn + k)) * 2 + 0] = cr;
      out[OUT_CENT + ((size_t)(b * Kn + k)) * 2 + 1] = cc;
      caL[k] = ca;
      entL[k] = -ea / 6.802394763324311f;  // log(900)
    }
    __syncthreads();
  }

  // ---- phase C: attended dots (features L3-hot from k_base's stream) ----
  const int lane = t & 63, wid = t >> 6;
  const float4* xq = (const float4*)(x + (size_t)b * Dn * HWn);
  for (int gi = 0; gi < 4; ++gi) {
    const int g = gi * 4 + wid;
    const int d0 = g * 8;
    float acc[8][5] = {};
    for (int i0 = 0; i0 < 4; ++i0) {
      const int i = i0 * 64 + lane;
      if (i < TQ) {
        float4 v[8];
#pragma unroll
        for (int j = 0; j < 8; ++j) v[j] = xq[(size_t)(d0 + j) * TQ + i];
        float w4[5][4];
#pragma unroll
        for (int k = 0; k < 5; ++k) {
          float4 wv4 = *(const float4*)&wl[k * HWn + 4 * i];
          w4[k][0] = wv4.x; w4[k][1] = wv4.y; w4[k][2] = wv4.z; w4[k][3] = wv4.w;
        }
#pragma unroll
        for (int j = 0; j < 8; ++j)
#pragma unroll
          for (int k = 0; k < 5; ++k)
            acc[j][k] += v[j].x * w4[k][0] + v[j].y * w4[k][1] +
                         v[j].z * w4[k][2] + v[j].w * w4[k][3];
      }
    }
#pragma unroll
    for (int j = 0; j < 8; ++j)
#pragma unroll
      for (int k = 0; k < 5; ++k) {
        float s = wsum(acc[j][k]);
        if (lane == 0) dots[k * Dn + d0 + j] = s;
      }
  }
  __syncthreads();

  // ---- phase D: LN-combine + wv proj + MLP + stop ----
  for (int i = t; i < Kn * Dn; i += 256) {
    int k = i >> 7, e = i & 127;
    af[i] = fn_g[e] * (dots[i] - caL[k]) + fn_b[e];
  }
  __syncthreads();
  for (int i = t; i < Kn * Dn; i += 256) {
    int k = i >> 7, d2 = i & 127;
    const float4* wr = (const float4*)(wv + (size_t)d2 * Dn);
    const float4* afq = (const float4*)&af[k << 7];
    float s = bv[d2];
    for (int e = 0; e < Dn / 4; ++e) {
      float4 a = afq[e], w = wr[e];
      s += a.x * w.x + a.y * w.y + a.z * w.z + a.w * w.w;
    }
    att[i] = s;
  }
  __syncthreads();
  for (int i = t; i < Kn * 64; i += 256) {
    int k = i >> 6, j = i & 63;
    const float* sr = sw1 + (size_t)j * (Dn + 1);
    float s = sb1[j];
    for (int e = 0; e < Dn; ++e) s += sr[e] * att[(k << 7) + e];
    s += entL[k] * sr[Dn];
    // exact GELU: x * (erf(x/sqrt(2)) + 1) / 2
    hbuf[i] = s * (erff(s * 0.7071067811865475f) + 1.0f) * 0.5f;
  }
  __syncthreads();
  if (t < Kn) {
    float s = sb2[0];
    for (int j = 0; j < 64; ++j) s += hbuf[(t << 6) + j] * sw2[j];
    out[OUT_STOP + (size_t)b * Kn + t] = s;
  }
}

// ---------------- launch ----------------
extern "C" void kernel_launch(void* const* d_in, const int* in_sizes, int n_in,
                              void* d_out, int out_size, void* d_ws, size_t ws_size,
                              hipStream_t stream) {
  (void)in_sizes; (void)n_in; (void)out_size; (void)ws_size;
  const float* features = (const float*)d_in[0];
  const float* clue     = (const float*)d_in[1];
  const float* wq       = (const float*)d_in[2];
  const float* bq       = (const float*)d_in[3];
  const float* wk       = (const float*)d_in[4];
  const float* bk       = (const float*)d_in[5];
  const float* wv       = (const float*)d_in[6];
  const float* bv       = (const float*)d_in[7];
  const float* sw1      = (const float*)d_in[8];
  const float* sb1      = (const float*)d_in[9];
  const float* sw2      = (const float*)d_in[10];
  const float* sb2      = (const float*)d_in[11];
  const float* qn_g     = (const float*)d_in[12];
  const float* qn_b     = (const float*)d_in[13];
  const float* fn_g     = (const float*)d_in[14];
  const float* fn_b     = (const float*)d_in[15];
  float* ws  = (float*)d_ws;
  float* out = (float*)d_out;

  // fold_in(key(42), k) on host: full threefry of (0,k) with key (0,42).
  FoldedKeys fk;
  for (int k = 0; k < Kn; ++k) {
    uint32_t x0 = 0u, x1 = (uint32_t)k;
    threefry2x32(0u, 42u, x0, x1);
    fk.k1[k] = x0; fk.k2[k] = x1;
  }

  hipLaunchKernelGGL(k_prep, dim3(Kn), dim3(128), 0, stream,
                     clue, wq, bq, wk, bk, qn_g, qn_b, fn_g, fn_b, ws);
  hipLaunchKernelGGL(k_base, dim3(2, Bn), dim3(256), 0, stream,
                     features, ws, out);
  hipLaunchKernelGGL(k_rest, dim3(Bn), dim3(256), 0, stream,
                     features, ws, wv, bv, sw1, sb1, sw2, sb2, fn_g, fn_b,
                     out, fk);
}

// Round 10
// 163.780 us; speedup vs baseline: 1.6192x; 1.6192x over previous
//
#include <hip/hip_runtime.h>
#include <stdint.h>
#include <math.h>

// ---------------- problem constants ----------------
namespace {
constexpr int Bn = 512, Dn = 128, Wn = 30, Kn = 5;
constexpr int HWn = 900;  // 30*30

// workspace float offsets (tiny: only per-query constants)
constexpr size_t OFF_A  = 0;                         // Kn*Dn = 640
constexpr size_t OFF_SA = OFF_A + (size_t)Kn * Dn;   // 5 (pad 8)
constexpr size_t OFF_C0 = OFF_SA + 8;                // 5 (pad 8)

// output float offsets (centroids, attention_maps, stop_logits concatenated)
constexpr size_t OUT_CENT = 0;
constexpr size_t OUT_ATTN = (size_t)Bn * Kn * 2;               // 5120
constexpr size_t OUT_STOP = OUT_ATTN + (size_t)Bn * Kn * HWn;  // 2309120
}  // namespace

struct FoldedKeys { uint32_t k1[5]; uint32_t k2[5]; };

// ---------------- threefry2x32 (JAX partitionable, 20 rounds) ----------------
__host__ __device__ static inline uint32_t rotl32(uint32_t x, int d) {
  return (x << d) | (x >> (32 - d));
}

__host__ __device__ static inline void threefry2x32(uint32_t k1, uint32_t k2,
                                                    uint32_t& x0, uint32_t& x1) {
  uint32_t k3 = k1 ^ k2 ^ 0x1BD11BDAu;
  x0 += k1; x1 += k2;
#define TF_R(rot) { x0 += x1; x1 = rotl32(x1, rot); x1 ^= x0; }
  TF_R(13) TF_R(15) TF_R(26) TF_R(6)   x0 += k2; x1 += k3 + 1u;
  TF_R(17) TF_R(29) TF_R(16) TF_R(24)  x0 += k3; x1 += k1 + 2u;
  TF_R(13) TF_R(15) TF_R(26) TF_R(6)   x0 += k1; x1 += k2 + 3u;
  TF_R(17) TF_R(29) TF_R(16) TF_R(24)  x0 += k2; x1 += k3 + 4u;
  TF_R(13) TF_R(15) TF_R(26) TF_R(6)   x0 += k3; x1 += k1 + 5u;
#undef TF_R
}

// ---------------- reduction helpers ----------------
__device__ static inline float wsum(float v) {
#pragma unroll
  for (int o = 32; o; o >>= 1) v += __shfl_xor(v, o, 64);
  return v;
}
__device__ static inline float bsum2(float v, float* scr) {  // 128-thread block
  v = wsum(v);
  if ((threadIdx.x & 63) == 0) scr[threadIdx.x >> 6] = v;
  __syncthreads();
  float r = scr[0] + scr[1];
  __syncthreads();
  return r;
}

// ---------------- kernel 0: per-query constants ----------------
// q = LN(clue)@wq.T+bq ; qk = q@wk ; A = fn_g*qk ; SA = sum A ; C0 = fn_b.qk + q.bk
__global__ __launch_bounds__(128) void k_prep(
    const float* __restrict__ clue, const float* __restrict__ wq,
    const float* __restrict__ bq, const float* __restrict__ wk,
    const float* __restrict__ bk, const float* __restrict__ qn_g,
    const float* __restrict__ qn_b, const float* __restrict__ fn_g,
    const float* __restrict__ fn_b, float* __restrict__ ws) {
  __shared__ float scr[2];
  __shared__ float lnc[Dn], qrow[Dn], qkrow[Dn];
  const int k = blockIdx.x, t = threadIdx.x;
  float xv = clue[(size_t)k * Dn + t];
  float m = bsum2(xv, scr) * (1.0f / Dn);
  float dd = xv - m;
  float var = bsum2(dd * dd, scr) * (1.0f / Dn);
  float r = 1.0f / sqrtf(var + 1e-5f);
  lnc[t] = dd * r * qn_g[t] + qn_b[t];
  __syncthreads();
  {
    float acc = bq[t];
    const float* wr = wq + (size_t)t * Dn;
    for (int e = 0; e < Dn; ++e) acc += lnc[e] * wr[e];
    qrow[t] = acc;
  }
  __syncthreads();
  {
    float acc = 0.f;
    for (int d = 0; d < Dn; ++d) acc += qrow[d] * wk[(size_t)d * Dn + t];
    qkrow[t] = acc;
    ws[OFF_A + (size_t)k * Dn + t] = fn_g[t] * acc;
  }
  __syncthreads();
  float sa = bsum2(fn_g[t] * qkrow[t], scr);
  float c0 = bsum2(fn_b[t] * qkrow[t] + qrow[t] * bk[t], scr);
  if (t == 0) {
    ws[OFF_SA + k] = sa;
    ws[OFF_C0 + k] = c0;
  }
}

// ---------------- kernel 1: everything per image, 1024 threads --------------
// 512 blocks x 1024 thr (16 waves); thread = ONE pixel -> tiny register state
// sized to fit the 64-VGPR allocator target without spilling (R6/R7 lesson).
// Phase A: stream image (4-deep scalar batches), LN stats + 5 base dots.
// Phase B: 5 gumbel-softmax steps with FIXED max (noisy<=50 -> p=exp(noisy-50);
//          ratios are exact) -> ONE 5-value reduction round per k:
//          Z, sum p*row, sum p*col, sum p*(noisy-50), sum p*m*r.
// Phase C: re-read own image for attended dots (L3-hot: whole 236 MB tensor
//          was streamed this dispatch; warp = 8 channels in two 4-ch halves).
// Phase D: LN-combine + wv projection + GELU MLP + stop logits.
__global__ __launch_bounds__(1024) void k_all(
    const float* __restrict__ x, const float* __restrict__ ws,
    const float* __restrict__ wv, const float* __restrict__ bv,
    const float* __restrict__ sw1, const float* __restrict__ sb1,
    const float* __restrict__ sw2, const float* __restrict__ sb2,
    const float* __restrict__ fn_g, const float* __restrict__ fn_b,
    float* __restrict__ out, FoldedKeys keys) {
  __shared__ float Al[Kn * Dn];   // phase A: fn_g*qk ; phase D: reused as af
  __shared__ float wl[Kn * HWn];  // w = attn*rstd
  __shared__ float dots[Kn * Dn];
  __shared__ float att[Kn * Dn];
  __shared__ float hbuf[Kn * 64];
  __shared__ float scrS[16 * 5];  // per-warp partials, 5 sums
  __shared__ float bcZ[4];        // broadcast 1/Z
  __shared__ float caL[8], entL[8];
  const int b = blockIdx.x, t = threadIdx.x;
  if (t < Kn * Dn) Al[t] = ws[OFF_A + t];
  __syncthreads();
  const bool act = (t < HWn);
  const float* xb = x + (size_t)b * Dn * HWn;

  // ---- phase A: stream this image once; 4 scalar loads in flight ----
  float sm = 0.f, sq = 0.f;
  float sd[5] = {};
  {
    const float* xt = xb + (act ? t : 0);
    for (int e0 = 0; e0 < Dn; e0 += 4) {
      float vb[4];
#pragma unroll
      for (int j = 0; j < 4; ++j) vb[j] = xt[(size_t)(e0 + j) * HWn];
#pragma unroll
      for (int j = 0; j < 4; ++j) {
        const int e = e0 + j;
        float v = vb[j];
        sm += v;
        sq += v * v;
        sd[0] += v * Al[e];
        sd[1] += v * Al[Dn + e];
        sd[2] += v * Al[2 * Dn + e];
        sd[3] += v * Al[3 * Dn + e];
        sd[4] += v * Al[4 * Dn + e];
      }
    }
  }
  float base[5], r, mr;
  {
    float m = sm * (1.0f / Dn);
    float var = sq * (1.0f / Dn) - m * m;
    r = 1.0f / sqrtf(var + 1e-5f);
    mr = m * r;
#pragma unroll
    for (int k = 0; k < 5; ++k)
      base[k] = (r * (sd[k] - m * ws[OFF_SA + k]) + ws[OFF_C0 + k]) *
                0.08838834764831844f;  // 1/sqrt(128)
  }
  const float rw = (float)(t / Wn), cl = (float)(t % Wn);
  float cum = 1.0f;

  // ---- phase B: 5 sequential gumbel-softmax steps, fixed max = 50 ----
  for (int k = 0; k < 5; ++k) {
    const uint32_t fk1 = keys.k1[k], fk2 = keys.k2[k];
    float noisy;
    if (act) {
      float s = base[k] + logf(cum);
      s = fminf(fmaxf(s, -50.f), 50.f);
      uint32_t x0 = 0u, x1 = (uint32_t)(b * HWn + t);  // counter = (0, j)
      threefry2x32(fk1, fk2, x0, x1);
      uint32_t bits = x0 ^ x1;
      float u = __uint_as_float((bits >> 9) | 0x3f800000u) - 1.0f;
      u = fmaxf(u, 1e-10f);
      float g = -logf(-logf(u));
      noisy = fminf(fmaxf(s + g, -50.f), 50.f);
    } else {
      noisy = -1e30f;
    }
    const float pl = noisy - 50.0f;      // log p (unnormalized)
    const float p = expf(pl);            // 0 for inactive lanes
    float P[5];
    P[0] = p; P[1] = p * rw; P[2] = p * cl; P[3] = p * pl; P[4] = p * mr;
#pragma unroll
    for (int q = 0; q < 5; ++q) P[q] = wsum(P[q]);
    if ((t & 63) == 0) {
      int w = t >> 6;
#pragma unroll
      for (int q = 0; q < 5; ++q) scrS[w * 5 + q] = P[q];
    }
    __syncthreads();
    if (t == 0) {
      float S0 = 0, S1 = 0, S2 = 0, S3 = 0, S4 = 0;
#pragma unroll
      for (int w = 0; w < 16; ++w) {
        S0 += scrS[w * 5 + 0]; S1 += scrS[w * 5 + 1]; S2 += scrS[w * 5 + 2];
        S3 += scrS[w * 5 + 3]; S4 += scrS[w * 5 + 4];
      }
      const float invZ = 1.0f / S0;
      out[OUT_CENT + ((size_t)(b * Kn + k)) * 2 + 0] = S1 * invZ;
      out[OUT_CENT + ((size_t)(b * Kn + k)) * 2 + 1] = S2 * invZ;
      caL[k] = S4 * invZ;
      // entropy: sum a*log a = S3/Z - log Z ; ent = -(that)/log(900)
      entL[k] = -(S3 * invZ - logf(S0)) * 0.14700905142472002f;  // 1/log(900)
      bcZ[0] = invZ;
    }
    __syncthreads();
    const float invZ = bcZ[0];
    if (act) {
      float a = p * invZ;
      out[OUT_ATTN + ((size_t)(b * Kn + k)) * HWn + t] = a;
      wl[(size_t)k * HWn + t] = a * r;
      cum = fmaxf(cum * (1.0f - 0.9f * a), 1e-6f);
    }
    __syncthreads();  // protect bcZ/scrS before next k
  }

  // ---- phase C: attended dots; warp = 8 channels in two 4-channel halves ----
  const int lane = t & 63, wid = t >> 6;
#pragma unroll
  for (int h = 0; h < 2; ++h) {
    const int d0 = wid * 8 + h * 4;
    float acc[4][5] = {};
    for (int i0 = 0; i0 < 15; ++i0) {
      const int i = i0 * 64 + lane;
      if (i < HWn) {
        float v[4];
#pragma unroll
        for (int j = 0; j < 4; ++j) v[j] = xb[(size_t)(d0 + j) * HWn + i];
        float w0 = wl[i], w1 = wl[HWn + i], w2 = wl[2 * HWn + i],
              w3 = wl[3 * HWn + i], w4 = wl[4 * HWn + i];
#pragma unroll
        for (int j = 0; j < 4; ++j) {
          acc[j][0] += v[j] * w0; acc[j][1] += v[j] * w1;
          acc[j][2] += v[j] * w2; acc[j][3] += v[j] * w3;
          acc[j][4] += v[j] * w4;
        }
      }
    }
#pragma unroll
    for (int j = 0; j < 4; ++j)
#pragma unroll
      for (int k = 0; k < 5; ++k) {
        float s = wsum(acc[j][k]);
        if (lane == 0) dots[k * Dn + d0 + j] = s;
      }
  }
  __syncthreads();

  // ---- phase D: LN-combine + wv proj + MLP + stop ----
  float* af = Al;  // reuse
  if (t < Kn * Dn) {
    int k = t >> 7, e = t & 127;
    af[t] = fn_g[e] * (dots[t] - caL[k]) + fn_b[e];
  }
  __syncthreads();
  if (t < Kn * Dn) {
    int k = t >> 7, d2 = t & 127;
    const float4* wr = (const float4*)(wv + (size_t)d2 * Dn);
    const float4* afq = (const float4*)&af[k << 7];
    float s = bv[d2];
    for (int e = 0; e < Dn / 4; ++e) {
      float4 a = afq[e], w = wr[e];
      s += a.x * w.x + a.y * w.y + a.z * w.z + a.w * w.w;
    }
    att[t] = s;
  }
  __syncthreads();
  if (t < Kn * 64) {
    int k = t >> 6, j = t & 63;
    const float* sr = sw1 + (size_t)j * (Dn + 1);
    float s = sb1[j];
    for (int e = 0; e < Dn; ++e) s += sr[e] * att[(k << 7) + e];
    s += entL[k] * sr[Dn];
    // exact GELU: x * (erf(x/sqrt(2)) + 1) / 2
    hbuf[t] = s * (erff(s * 0.7071067811865475f) + 1.0f) * 0.5f;
  }
  __syncthreads();
  if (t < Kn) {
    float s = sb2[0];
    for (int j = 0; j < 64; ++j) s += hbuf[(t << 6) + j] * sw2[j];
    out[OUT_STOP + (size_t)b * Kn + t] = s;
  }
}

// ---------------- launch ----------------
extern "C" void kernel_launch(void* const* d_in, const int* in_sizes, int n_in,
                              void* d_out, int out_size, void* d_ws, size_t ws_size,
                              hipStream_t stream) {
  (void)in_sizes; (void)n_in; (void)out_size; (void)ws_size;
  const float* features = (const float*)d_in[0];
  const float* clue     = (const float*)d_in[1];
  const float* wq       = (const float*)d_in[2];
  const float* bq       = (const float*)d_in[3];
  const float* wk       = (const float*)d_in[4];
  const float* bk       = (const float*)d_in[5];
  const float* wv       = (const float*)d_in[6];
  const float* bv       = (const float*)d_in[7];
  const float* sw1      = (const float*)d_in[8];
  const float* sb1      = (const float*)d_in[9];
  const float* sw2      = (const float*)d_in[10];
  const float* sb2      = (const float*)d_in[11];
  const float* qn_g     = (const float*)d_in[12];
  const float* qn_b     = (const float*)d_in[13];
  const float* fn_g     = (const float*)d_in[14];
  const float* fn_b     = (const float*)d_in[15];
  float* ws  = (float*)d_ws;
  float* out = (float*)d_out;

  // fold_in(key(42), k) on host: full threefry of (0,k) with key (0,42).
  FoldedKeys fk;
  for (int k = 0; k < Kn; ++k) {
    uint32_t x0 = 0u, x1 = (uint32_t)k;
    threefry2x32(0u, 42u, x0, x1);
    fk.k1[k] = x0; fk.k2[k] = x1;
  }

  hipLaunchKernelGGL(k_prep, dim3(Kn), dim3(128), 0, stream,
                     clue, wq, bq, wk, bk, qn_g, qn_b, fn_g, fn_b, ws);
  hipLaunchKernelGGL(k_all, dim3(Bn), dim3(1024), 0, stream,
                     features, ws, wv, bv, sw1, sb1, sw2, sb2, fn_g, fn_b,
                     out, fk);
}